// Round 6
// baseline (45.585 us; speedup 1.0000x reference)
//
#include <hip/hip_runtime.h>
#include <hip/hip_bf16.h>

// Segment-mean over sorted indexes — dynamic work queue, whole-token waves.
// hidden: [B=8, S=2048, D=768] f32; ori_indexes: [B, S] sorted int (<T=1024)
// out:    [B, T, D] f32 = segment_sum / clip(count,1)
//
// R3 (static wave-per-token, 19.8us) ends on the unluckiest CU: 1x-resident
// grid has zero backfill and per-CU token-row sums are Poisson(64) (max CU
// ~ +35%). Here tokens are popped from 8 per-batch atomic queues (one per
// slice = batch, counters 128B apart in d_ws, zeroed by a captured
// hipMemsetAsync). Fast waves pop more tokens -> per-CU load converges to
// the slice mean (slices differ by ~3%). Work shape per wave is IDENTICAL
// to R3: whole token, lane covers float4 cols {l,l+64,l+128}, unroll x2,
// nontemporal. Output written exactly once, deterministic.

#define SGA_B 8
#define SGA_S 2048
#define SGA_D 768
#define SGA_T 1024
#define SGA_NV (SGA_D / 4)   // 192 float4 per row
#define SGA_CTR_STRIDE 32    // ints; 128B between slice counters

typedef float f32x4 __attribute__((ext_vector_type(4)));

__global__ __launch_bounds__(256) void sga_queue_kernel(
    const float* __restrict__ hidden,
    const int* __restrict__ idx,
    float* __restrict__ out,
    int* __restrict__ ctrs) {
    const int lane = threadIdx.x & 63;
    const int b = blockIdx.x & 7;          // slice = batch
    int* ctr = ctrs + b * SGA_CTR_STRIDE;

    const int* __restrict__ ib = idx + b * SGA_S;
    const f32x4* __restrict__ hbase =
        reinterpret_cast<const f32x4*>(hidden) + (size_t)b * SGA_S * SGA_NV + lane;
    f32x4* __restrict__ obat =
        reinterpret_cast<f32x4*>(out) + (size_t)b * SGA_T * SGA_NV + lane;

    for (;;) {
        int t;
        if (lane == 0) t = atomicAdd(ctr, 1);
        t = __shfl(t, 0);
        if (t >= SGA_T) break;

        // token t's rows = [lower_bound(t), lower_bound(t+1)) (wave-uniform,
        // L1-resident; whole CU works the same batch row -> hot)
        int lo = 0, hi = SGA_S;
        while (lo < hi) { int m = (lo + hi) >> 1; if (ib[m] < t) lo = m + 1; else hi = m; }
        const int s0 = lo;
        hi = SGA_S;
        while (lo < hi) { int m = (lo + hi) >> 1; if (ib[m] < t + 1) lo = m + 1; else hi = m; }
        const int s1 = lo;

        f32x4 a0 = (f32x4)0.f, a1 = (f32x4)0.f, a2 = (f32x4)0.f;
        int s = s0;
        for (; s + 1 < s1; s += 2) {
            const f32x4* r0 = hbase + (size_t)s * SGA_NV;
            const f32x4* r1 = r0 + SGA_NV;
            f32x4 v00 = __builtin_nontemporal_load(r0);
            f32x4 v01 = __builtin_nontemporal_load(r0 + 64);
            f32x4 v02 = __builtin_nontemporal_load(r0 + 128);
            f32x4 v10 = __builtin_nontemporal_load(r1);
            f32x4 v11 = __builtin_nontemporal_load(r1 + 64);
            f32x4 v12 = __builtin_nontemporal_load(r1 + 128);
            a0 += v00; a1 += v01; a2 += v02;
            a0 += v10; a1 += v11; a2 += v12;
        }
        if (s < s1) {
            const f32x4* rp = hbase + (size_t)s * SGA_NV;
            a0 += __builtin_nontemporal_load(rp);
            a1 += __builtin_nontemporal_load(rp + 64);
            a2 += __builtin_nontemporal_load(rp + 128);
        }

        const int cnt = s1 - s0;
        const float inv = (cnt > 0) ? (1.0f / (float)cnt) : 0.0f;
        a0 *= inv; a1 *= inv; a2 *= inv;

        f32x4* o = obat + (size_t)t * SGA_NV;
        __builtin_nontemporal_store(a0, o);
        __builtin_nontemporal_store(a1, o + 64);
        __builtin_nontemporal_store(a2, o + 128);
    }
}

// Fallback: R3 static wave-per-token (19.8us), used only if ws is unusable.
__global__ __launch_bounds__(256) void sga_static_kernel(
    const float* __restrict__ hidden,
    const int* __restrict__ idx,
    float* __restrict__ out) {
    const int b = blockIdx.y;
    const int wid = threadIdx.x >> 6;
    const int lane = threadIdx.x & 63;
    const int t = blockIdx.x * 4 + wid;
    const int* __restrict__ ib = idx + b * SGA_S;
    int lo = 0, hi = SGA_S;
    while (lo < hi) { int m = (lo + hi) >> 1; if (ib[m] < t) lo = m + 1; else hi = m; }
    const int s0 = lo;
    hi = SGA_S;
    while (lo < hi) { int m = (lo + hi) >> 1; if (ib[m] < t + 1) lo = m + 1; else hi = m; }
    const int s1 = lo;
    const f32x4* __restrict__ hbase =
        reinterpret_cast<const f32x4*>(hidden) + (size_t)b * SGA_S * SGA_NV + lane;
    f32x4 a0 = (f32x4)0.f, a1 = (f32x4)0.f, a2 = (f32x4)0.f;
    int s = s0;
    for (; s + 1 < s1; s += 2) {
        const f32x4* r0 = hbase + (size_t)s * SGA_NV;
        const f32x4* r1 = r0 + SGA_NV;
        a0 += __builtin_nontemporal_load(r0);
        a1 += __builtin_nontemporal_load(r0 + 64);
        a2 += __builtin_nontemporal_load(r0 + 128);
        a0 += __builtin_nontemporal_load(r1);
        a1 += __builtin_nontemporal_load(r1 + 64);
        a2 += __builtin_nontemporal_load(r1 + 128);
    }
    if (s < s1) {
        const f32x4* rp = hbase + (size_t)s * SGA_NV;
        a0 += __builtin_nontemporal_load(rp);
        a1 += __builtin_nontemporal_load(rp + 64);
        a2 += __builtin_nontemporal_load(rp + 128);
    }
    const float inv = (s1 > s0) ? (1.0f / (float)(s1 - s0)) : 0.0f;
    a0 *= inv; a1 *= inv; a2 *= inv;
    f32x4* o = reinterpret_cast<f32x4*>(out) + ((size_t)b * SGA_T + t) * SGA_NV + lane;
    __builtin_nontemporal_store(a0, o);
    __builtin_nontemporal_store(a1, o + 64);
    __builtin_nontemporal_store(a2, o + 128);
}

extern "C" void kernel_launch(void* const* d_in, const int* in_sizes, int n_in,
                              void* d_out, int out_size, void* d_ws, size_t ws_size,
                              hipStream_t stream) {
    const float* hidden = (const float*)d_in[0];
    const int* idx = (const int*)d_in[1];
    float* out = (float*)d_out;

    const size_t ctr_bytes = (size_t)SGA_B * SGA_CTR_STRIDE * sizeof(int);
    if (d_ws != nullptr && ws_size >= ctr_bytes) {
        int* ctrs = (int*)d_ws;
        hipMemsetAsync(ctrs, 0, ctr_bytes, stream);
        sga_queue_kernel<<<dim3(2048, 1, 1), dim3(256, 1, 1), 0, stream>>>(
            hidden, idx, out, ctrs);
    } else {
        sga_static_kernel<<<dim3(SGA_T / 4, SGA_B, 1), dim3(256, 1, 1), 0, stream>>>(
            hidden, idx, out);
    }
}

// Round 7
// 17.807 us; speedup vs baseline: 2.5600x; 2.5600x over previous
//
#include <hip/hip_runtime.h>
#include <hip/hip_bf16.h>

// Segment-mean over sorted indexes — R3 skeleton + wave-parallel 64-ary
// search + XCD-chunked block swizzle.
// hidden: [B=8, S=2048, D=768] f32; ori_indexes: [B, S] sorted int (<T=1024)
// out:    [B, T, D] f32 = segment_sum / clip(count,1)
//
// Block = 256 threads = 4 waves; wave owns one token. Token rows =
// [lower_bound(t), lower_bound(t+1)), found by a 2-round wave-parallel
// 64-ary search (stride-32 probe + stride-1 probe, __ballot/popcount) —
// 2-3 PARALLEL index loads instead of ~22 dependent ones, killing the
// serial prologue all 8192 waves paid at kernel start in R3.
// Block swizzle: blocks round-robin XCDs, so w=(bid&7)*256+(bid>>3) gives
// XCD k exactly batch k -> each XCD streams one contiguous 6.3MB read /
// 3.1MB write slab, fully L2-local (2048%8==0, bijective).
// Every output element written exactly once (empty token -> inv=0 -> zeros);
// deterministic; single dispatch; no workspace.

#define SGA_B 8
#define SGA_S 2048
#define SGA_D 768
#define SGA_T 1024
#define SGA_NV (SGA_D / 4)   // 192 float4 per row

typedef float f32x4 __attribute__((ext_vector_type(4)));

__global__ __launch_bounds__(256) void sga_segmean_kernel(
    const float* __restrict__ hidden,
    const int* __restrict__ idx,
    float* __restrict__ out) {
    const int wid = threadIdx.x >> 6;
    const int lane = threadIdx.x & 63;

    // XCD-chunked swizzle (dispatch round-robins XCDs; 2048 blocks % 8 == 0)
    const int w = ((blockIdx.x & 7) << 8) | ((int)blockIdx.x >> 3);
    const int b = w >> 8;                   // batch == XCD
    const int t = ((w & 255) << 2) | wid;   // token 0..1023

    const int* __restrict__ ib = idx + b * SGA_S;

    // --- wave-parallel 64-ary lower_bound for t and t+1 ---
    // Round 1: stride-32 probes cover [0,2048). ka = #probes < t gives the
    // 32-wide bracket: all i < base_a have ib[i] < t, and lb(t) <= base_a+32.
    const int p1 = ib[lane << 5];
    const int ka = __builtin_popcountll(__ballot(p1 < t));
    const int kb = __builtin_popcountll(__ballot(p1 < t + 1));
    const int base_a = ka ? ((ka - 1) << 5) : 0;
    const int base_b = kb ? ((kb - 1) << 5) : 0;

    // Round 2: stride-1 probes of [base, base+64) finish the bound.
    const int ia = base_a + lane;
    const int pa = ib[ia < SGA_S ? ia : (SGA_S - 1)];
    const int s0 = base_a +
        __builtin_popcountll(__ballot(ia < SGA_S && pa < t));
    int s1;
    if (base_b == base_a) {  // wave-uniform; common case (small tokens)
        s1 = base_b + __builtin_popcountll(__ballot(ia < SGA_S && pa < t + 1));
    } else {
        const int ibx = base_b + lane;
        const int pb = ib[ibx < SGA_S ? ibx : (SGA_S - 1)];
        s1 = base_b + __builtin_popcountll(__ballot(ibx < SGA_S && pb < t + 1));
    }

    // --- stream rows [s0, s1), lane covers float4 cols {l, l+64, l+128} ---
    const f32x4* __restrict__ hbase =
        reinterpret_cast<const f32x4*>(hidden) + (size_t)b * SGA_S * SGA_NV + lane;

    f32x4 a0 = (f32x4)0.f, a1 = (f32x4)0.f, a2 = (f32x4)0.f;
    int s = s0;
    for (; s + 1 < s1; s += 2) {
        const f32x4* r0 = hbase + (size_t)s * SGA_NV;
        const f32x4* r1 = r0 + SGA_NV;
        f32x4 v00 = __builtin_nontemporal_load(r0);
        f32x4 v01 = __builtin_nontemporal_load(r0 + 64);
        f32x4 v02 = __builtin_nontemporal_load(r0 + 128);
        f32x4 v10 = __builtin_nontemporal_load(r1);
        f32x4 v11 = __builtin_nontemporal_load(r1 + 64);
        f32x4 v12 = __builtin_nontemporal_load(r1 + 128);
        a0 += v00; a1 += v01; a2 += v02;
        a0 += v10; a1 += v11; a2 += v12;
    }
    if (s < s1) {
        const f32x4* rp = hbase + (size_t)s * SGA_NV;
        a0 += __builtin_nontemporal_load(rp);
        a1 += __builtin_nontemporal_load(rp + 64);
        a2 += __builtin_nontemporal_load(rp + 128);
    }

    const int cnt = s1 - s0;
    const float inv = (cnt > 0) ? (1.0f / (float)cnt) : 0.0f;
    a0 *= inv; a1 *= inv; a2 *= inv;

    f32x4* __restrict__ o =
        reinterpret_cast<f32x4*>(out) + ((size_t)b * SGA_T + t) * SGA_NV + lane;
    __builtin_nontemporal_store(a0, o);
    __builtin_nontemporal_store(a1, o + 64);
    __builtin_nontemporal_store(a2, o + 128);
}

extern "C" void kernel_launch(void* const* d_in, const int* in_sizes, int n_in,
                              void* d_out, int out_size, void* d_ws, size_t ws_size,
                              hipStream_t stream) {
    const float* hidden = (const float*)d_in[0];
    const int* idx = (const int*)d_in[1];
    float* out = (float*)d_out;

    dim3 grid(SGA_B * SGA_T / 4, 1, 1);   // 2048 blocks x 256 threads (4 waves)
    sga_segmean_kernel<<<grid, dim3(256, 1, 1), 0, stream>>>(hidden, idx, out);
}